// Round 10
// baseline (1163.216 us; speedup 1.0000x reference)
//
#include <hip/hip_runtime.h>
#include <float.h>

#define WDIM 96
#define HW   9216
#define PH   98
#define IMG  (PH*PH)            // 9604
#define NPIXP (2*IMG)           // 19208 real padded pixels
#define NPIX 19328              // 151*128 compute pixels
#define GUARD 128
#define GPIX (NPIX + 2*GUARD)   // 19584
#define NKG_ACT 96              // kg planes per activation buffer (768/8)
#define MDIM 768                // padded cout
#define G3 816                  // conv3x3 kg rows (9*90=810, padded)
#define G1 96                   // 1x1 kg rows (90 real, padded)

typedef _Float16 f16;
typedef f16  f16x8 __attribute__((ext_vector_type(8)));
typedef f16  f16x4 __attribute__((ext_vector_type(4)));
typedef float f32x16 __attribute__((ext_vector_type(16)));

// ---------------- prep: fold bias+BN into alpha/beta (padded to 768); l2-normalize protos ----
__global__ void prep_kernel(
    const float* __restrict__ cls_b,
    const float* __restrict__ g0, const float* __restrict__ b0,
    const float* __restrict__ rm0, const float* __restrict__ rv0,
    const float* __restrict__ p1b,
    const float* __restrict__ g1, const float* __restrict__ b1,
    const float* __restrict__ rm1, const float* __restrict__ rv1,
    const float* __restrict__ p2b,
    const float* __restrict__ protos,
    float* __restrict__ alpha, float* __restrict__ beta,
    float* __restrict__ protoN)
{
    __shared__ float red[4];
    if (blockIdx.x == 0) {
        for (int i = threadIdx.x; i < MDIM; i += blockDim.x) {
            if (i < 720) {
                float s0 = g0[i] * rsqrtf(rv0[i] + 1e-5f);
                alpha[i] = s0;
                beta[i]  = (cls_b[i] - rm0[i]) * s0 + b0[i];
                float s1 = g1[i] * rsqrtf(rv1[i] + 1e-5f);
                alpha[MDIM + i] = s1;
                beta[MDIM + i]  = (p1b[i] - rm1[i]) * s1 + b1[i];
                alpha[2*MDIM + i] = 1.0f;
                beta[2*MDIM + i]  = p2b[i];
            } else {
                alpha[i] = 0.f; beta[i] = 0.f;
                alpha[MDIM + i] = 0.f; beta[MDIM + i] = 0.f;
                alpha[2*MDIM + i] = 0.f; beta[2*MDIM + i] = 0.f;
            }
        }
    } else {
        int row = blockIdx.x - 1;              // 0..19
        const float* src = protos + row * 720;
        float s = 0.f;
        for (int i = threadIdx.x; i < 720; i += blockDim.x) { float v = src[i]; s += v * v; }
        #pragma unroll
        for (int off = 32; off > 0; off >>= 1) s += __shfl_down(s, off);
        int wave = threadIdx.x >> 6, lane = threadIdx.x & 63;
        if (lane == 0) red[wave] = s;
        __syncthreads();
        float tot = red[0] + red[1] + red[2] + red[3];
        float rn = 1.0f / fmaxf(sqrtf(tot), 1e-12f);
        for (int i = threadIdx.x; i < 720; i += blockDim.x)
            protoN[row * 720 + i] = src[i] * rn;
    }
}

// ---------------- weight transform: OIHW -> split-fp16 K8-packed [kg][cout 768][8] ----------
// conv3x3 K-order is kgl-MAJOR, shift-minor: g = kgl*9 + s (matches mfma_gemm).
__global__ void wtrans_kernel(const float* __restrict__ w3,
                              const float* __restrict__ w1a,
                              const float* __restrict__ w1b,
                              f16* __restrict__ W3h, f16* __restrict__ W3l,
                              f16* __restrict__ W1ah, f16* __restrict__ W1al,
                              f16* __restrict__ W1bh, f16* __restrict__ W1bl)
{
    int tid = blockIdx.x * blockDim.x + threadIdx.x;
    const int N3 = G3 * MDIM;
    const int N1 = G1 * MDIM;
    const float* src; f16 *dh, *dl; int g, o, which;
    if (tid < N3)              { g = tid / MDIM; o = tid - g * MDIM; src = w3;  dh = W3h;  dl = W3l;  which = 0; }
    else if (tid < N3 + N1)    { int u = tid - N3;      g = u / MDIM; o = u - g * MDIM; src = w1a; dh = W1ah; dl = W1al; which = 1; }
    else if (tid < N3 + 2*N1)  { int u = tid - N3 - N1; g = u / MDIM; o = u - g * MDIM; src = w1b; dh = W1bh; dl = W1bl; which = 1; }
    else return;

    float v[8];
    #pragma unroll
    for (int j = 0; j < 8; ++j) v[j] = 0.f;
    if (which == 0) {
        if (g < 810 && o < 720) {
            int kgl = g / 9; int s = g - kgl * 9; int cin0 = kgl * 8;
            #pragma unroll
            for (int j = 0; j < 8; ++j)
                v[j] = src[((size_t)o * 720 + cin0 + j) * 9 + s];
        }
    } else {
        if (g < 90 && o < 720) {
            #pragma unroll
            for (int j = 0; j < 8; ++j)
                v[j] = src[(size_t)o * 720 + g * 8 + j];
        }
    }
    f16x8 hv, lv;
    #pragma unroll
    for (int j = 0; j < 8; ++j) {
        f16 h = (f16)v[j];
        hv[j] = h;
        lv[j] = (f16)(v[j] - (float)h);
    }
    size_t off = ((size_t)g * MDIM + o) * 8;
    *(f16x8*)(dh + off) = hv;
    *(f16x8*)(dl + off) = lv;
}

// ---------------- upsample+concat -> split-fp16 K8-packed padded-image planes ---------------
__global__ void upsample_kernel(const float* __restrict__ f1,
                                const float* __restrict__ f2,
                                const float* __restrict__ f3,
                                const float* __restrict__ f4,
                                f16* __restrict__ Xhi, f16* __restrict__ Xlo)
{
    int tid = blockIdx.x * blockDim.x + threadIdx.x;
    if (tid >= 90 * GPIX) return;
    int kg = tid / GPIX;
    int gp = tid - kg * GPIX;
    int p  = gp - GUARD;
    float v[8];
    #pragma unroll
    for (int j = 0; j < 8; ++j) v[j] = 0.f;
    if (p >= 0 && p < NPIXP) {
        int b = p / IMG; int rem = p - b * IMG;
        int y = rem / PH; int x = rem - y * PH;
        if (y >= 1 && y <= 96 && x >= 1 && x <= 96) {
            int oy = y - 1, ox = x - 1;
            int c0 = kg * 8;
            if (c0 < 48) {
                #pragma unroll
                for (int j = 0; j < 8; ++j)
                    v[j] = f1[((size_t)(b * 48 + c0 + j)) * HW + oy * 96 + ox];
            } else {
                const float* src; int Cs, Hs, cb;
                if (c0 < 144)      { src = f2; Cs = 96;  Hs = 48; cb = c0 - 48; }
                else if (c0 < 336) { src = f3; Cs = 192; Hs = 24; cb = c0 - 144; }
                else               { src = f4; Cs = 384; Hs = 12; cb = c0 - 336; }
                float scale = (float)(Hs - 1) / 95.0f;
                float yf = oy * scale, xf = ox * scale;
                int y0 = (int)yf, x0 = (int)xf;
                float wy = yf - y0, wx = xf - x0;
                int y1 = min(y0 + 1, Hs - 1), x1 = min(x0 + 1, Hs - 1);
                #pragma unroll
                for (int j = 0; j < 8; ++j) {
                    const float* sb = src + (size_t)(b * Cs + cb + j) * Hs * Hs;
                    float v00 = sb[y0 * Hs + x0], v01 = sb[y0 * Hs + x1];
                    float v10 = sb[y1 * Hs + x0], v11 = sb[y1 * Hs + x1];
                    float r0 = v00 * (1.f - wy) + v10 * wy;
                    float r1 = v01 * (1.f - wy) + v11 * wy;
                    v[j] = r0 * (1.f - wx) + r1 * wx;
                }
            }
        }
    }
    f16x8 hv, lv;
    #pragma unroll
    for (int j = 0; j < 8; ++j) {
        f16 h = (f16)v[j];
        hv[j] = h;
        lv[j] = (f16)(v[j] - (float)h);
    }
    size_t off = (size_t)tid * 8;
    *(f16x8*)(Xhi + off) = hv;
    *(f16x8*)(Xlo + off) = lv;
}

// ---------------- split-fp16 MFMA implicit-GEMM conv: barrier-free, 32x32x16 MFMA ------------
// 32x32x16 doubles FLOP per fragment byte vs 16x16x32 (24 vs 12 FLOP/B for the hh+hl+lh
// triple) — halves the L1/L2 fragment bandwidth that capped round 9 at ~52% MfmaUtil.
// Lane mapping (K8-packed friendly): A/B operand: row/col = lane&31, kg = lane>>5 (8
// contiguous k per lane = one kg slab). C/D: col=lane&31, row=(reg&3)+8*(reg>>2)+4*(lane>>5).
// Per K=16 step: 8 fragment loads (16B/lane each), 12 MFMAs. No LDS, no __syncthreads.
template<int NSTEP, int CONV3>
__global__ __launch_bounds__(256, 3)
void mfma_gemm(const f16* __restrict__ Whi, const f16* __restrict__ Wlo,
               const f16* __restrict__ Bhi_, const f16* __restrict__ Blo_,
               f16* __restrict__ Ohi, f16* __restrict__ Olo,
               const float* __restrict__ alpha, const float* __restrict__ beta,
               int relu)
{
    const int l = blockIdx.x;
    const int xcd = l & 7;
    const int j0 = l >> 3;                // 0..113
    const int ncol = xcd * 19 + j0 / 6;   // 19 n-columns per XCD band
    if (ncol >= 151) return;
    const int m0 = (j0 % 6) * 128;
    const int n0 = ncol * 128;

    const int t = threadIdx.x;
    const int lane = t & 63, wid = t >> 6;
    const int wm = wid >> 1, wn = wid & 1;
    const int half = lane >> 5, l32 = lane & 31;

    f32x16 acc[2][2];
    #pragma unroll
    for (int i = 0; i < 2; ++i)
        #pragma unroll
        for (int j = 0; j < 2; ++j)
            #pragma unroll
            for (int r = 0; r < 16; ++r)
                acc[i][j][r] = 0.f;

    // A fragment base: row = m0 + wm*64 + mt*32 + l32, kg = 2*step + half
    const int arow = m0 + wm * 64 + l32;
    const f16* Ah0 = Whi + ((size_t)half * MDIM + arow) * 8;
    const f16* Al0 = Wlo + ((size_t)half * MDIM + arow) * 8;
    const size_t astep = (size_t)2 * MDIM * 8;
    // B fragment base col
    const int bcol = n0 + wn * 64 + l32;

    for (int step = 0; step < NSTEP; ++step) {
        const int g = step * 2 + half;         // kg for this lane-half
        long long brow;
        if (CONV3) {
            int kgl = g / 9;
            int s = g - kgl * 9;
            int d = (s / 3 - 1) * PH + (s % 3 - 1);
            brow = (long long)kgl * GPIX + d;
        } else {
            brow = (long long)g * GPIX;
        }
        const f16* bh = Bhi_ + (brow + bcol) * 8;
        const f16* bl = Blo_ + (brow + bcol) * 8;
        const f16* Ah = Ah0 + (size_t)step * astep;
        const f16* Al = Al0 + (size_t)step * astep;

        f16x8 avh[2], avl[2], bvh[2], bvl[2];
        #pragma unroll
        for (int mt = 0; mt < 2; ++mt) {
            avh[mt] = *(const f16x8*)(Ah + mt * 256);   // mt*32 rows * 8
            avl[mt] = *(const f16x8*)(Al + mt * 256);
        }
        #pragma unroll
        for (int nt = 0; nt < 2; ++nt) {
            bvh[nt] = *(const f16x8*)(bh + nt * 256);
            bvl[nt] = *(const f16x8*)(bl + nt * 256);
        }
        // split-fp16: hh + hl + lh
        #pragma unroll
        for (int mt = 0; mt < 2; ++mt)
            #pragma unroll
            for (int nt = 0; nt < 2; ++nt) {
                acc[mt][nt] = __builtin_amdgcn_mfma_f32_32x32x16_f16(avh[mt], bvh[nt], acc[mt][nt], 0, 0, 0);
                acc[mt][nt] = __builtin_amdgcn_mfma_f32_32x32x16_f16(avh[mt], bvl[nt], acc[mt][nt], 0, 0, 0);
                acc[mt][nt] = __builtin_amdgcn_mfma_f32_32x32x16_f16(avl[mt], bvh[nt], acc[mt][nt], 0, 0, 0);
            }
    }

    // ---- epilogue: C/D row = (reg&3) + 8*(reg>>2) + 4*half, col = l32 ----
    #pragma unroll
    for (int mt = 0; mt < 2; ++mt) {
        #pragma unroll
        for (int nt = 0; nt < 2; ++nt) {
            const int P = n0 + wn * 64 + nt * 32 + l32;
            #pragma unroll
            for (int q = 0; q < 4; ++q) {
                const int rowb = m0 + wm * 64 + mt * 32 + q * 8 + half * 4;  // channel of reg 4q
                const float4 a4 = *(const float4*)(alpha + rowb);
                const float4 b4 = *(const float4*)(beta + rowb);
                float v0 = acc[mt][nt][4*q + 0] * a4.x + b4.x;
                float v1 = acc[mt][nt][4*q + 1] * a4.y + b4.y;
                float v2 = acc[mt][nt][4*q + 2] * a4.z + b4.z;
                float v3 = acc[mt][nt][4*q + 3] * a4.w + b4.w;
                if (relu) {
                    v0 = fmaxf(v0, 0.f); v1 = fmaxf(v1, 0.f);
                    v2 = fmaxf(v2, 0.f); v3 = fmaxf(v3, 0.f);
                }
                f16 h0 = (f16)v0, h1 = (f16)v1, h2 = (f16)v2, h3 = (f16)v3;
                f16x4 hv = {h0, h1, h2, h3};
                f16x4 lv = {(f16)(v0 - (float)h0), (f16)(v1 - (float)h1),
                            (f16)(v2 - (float)h2), (f16)(v3 - (float)h3)};
                const size_t kg = rowb >> 3;
                const int sub = rowb & 7;                 // 0 or 4
                size_t o = (kg * GPIX + P) * 8 + sub;
                *(f16x4*)(Ohi + o) = hv;
                *(f16x4*)(Olo + o) = lv;
            }
        }
    }
}

// ---------------- head: LN(720) -> l2norm -> proto dots -> max -> LN(2) ----------------------
__global__ __launch_bounds__(64)
void head_kernel(const f16* __restrict__ Yhi, const f16* __restrict__ Ylo,  // at GUARD
                 const float* __restrict__ lng, const float* __restrict__ lnb,
                 const float* __restrict__ protoN,
                 const float* __restrict__ lmg, const float* __restrict__ lmb,
                 float* __restrict__ out)
{
    int p = blockIdx.x * blockDim.x + threadIdx.x;   // 0..18431
    int b = p / HW; int r = p - b * HW;
    int y = r / 96; int x = r - y * 96;
    size_t P = (size_t)b * IMG + (y + 1) * PH + (x + 1);

    float s1 = 0.f, s2 = 0.f;
    for (int kg = 0; kg < 90; ++kg) {
        f16x8 hv = *(const f16x8*)(Yhi + ((size_t)kg * GPIX + P) * 8);
        f16x8 lv = *(const f16x8*)(Ylo + ((size_t)kg * GPIX + P) * 8);
        #pragma unroll
        for (int j = 0; j < 8; ++j) {
            float v = (float)hv[j] + (float)lv[j];
            s1 += v; s2 += v * v;
        }
    }
    float mu  = s1 * (1.0f / 720.0f);
    float var = s2 * (1.0f / 720.0f) - mu * mu;
    float inv = rsqrtf(var + 1e-5f);

    float dots[20];
    #pragma unroll
    for (int j = 0; j < 20; ++j) dots[j] = 0.f;
    float nrm = 0.f;
    for (int kg = 0; kg < 90; ++kg) {
        f16x8 hv = *(const f16x8*)(Yhi + ((size_t)kg * GPIX + P) * 8);
        f16x8 lv = *(const f16x8*)(Ylo + ((size_t)kg * GPIX + P) * 8);
        #pragma unroll
        for (int j = 0; j < 8; ++j) {
            int c = kg * 8 + j;
            float v = ((float)hv[j] + (float)lv[j] - mu) * inv * lng[c] + lnb[c];
            nrm += v * v;
            #pragma unroll
            for (int k = 0; k < 20; ++k)
                dots[k] = fmaf(v, protoN[k * 720 + c], dots[k]);
        }
    }
    float rn = 1.0f / fmaxf(sqrtf(nrm), 1e-12f);
    float m0v = -FLT_MAX, m1v = -FLT_MAX;
    #pragma unroll
    for (int j = 0; j < 10; ++j) m0v = fmaxf(m0v, dots[j]);
    #pragma unroll
    for (int j = 10; j < 20; ++j) m1v = fmaxf(m1v, dots[j]);
    m0v *= rn; m1v *= rn;
    float mu2 = 0.5f * (m0v + m1v);
    float dv  = m0v - mu2;
    float va  = dv * dv;
    float iv  = rsqrtf(va + 1e-5f);
    float o0 = (m0v - mu2) * iv * lmg[0] + lmb[0];
    float o1 = (m1v - mu2) * iv * lmg[1] + lmb[1];
    out[b * (2 * HW) + r]      = o0;
    out[b * (2 * HW) + HW + r] = o1;
}

extern "C" void kernel_launch(void* const* d_in, const int* in_sizes, int n_in,
                              void* d_out, int out_size, void* d_ws, size_t ws_size,
                              hipStream_t stream)
{
    const float* feat1      = (const float*)d_in[0];
    const float* feat2      = (const float*)d_in[1];
    const float* feat3      = (const float*)d_in[2];
    const float* feat4      = (const float*)d_in[3];
    const float* cls_w      = (const float*)d_in[4];
    const float* cls_b      = (const float*)d_in[5];
    const float* cls_bn_g   = (const float*)d_in[6];
    const float* cls_bn_b   = (const float*)d_in[7];
    const float* cls_bn_rm  = (const float*)d_in[8];
    const float* cls_bn_rv  = (const float*)d_in[9];
    const float* proj_w1    = (const float*)d_in[10];
    const float* proj_b1    = (const float*)d_in[11];
    const float* proj_bn_g  = (const float*)d_in[12];
    const float* proj_bn_b  = (const float*)d_in[13];
    const float* proj_bn_rm = (const float*)d_in[14];
    const float* proj_bn_rv = (const float*)d_in[15];
    const float* proj_w2    = (const float*)d_in[16];
    const float* proj_b2    = (const float*)d_in[17];
    const float* ln_feat_g  = (const float*)d_in[18];
    const float* ln_feat_b  = (const float*)d_in[19];
    const float* ln_mask_g  = (const float*)d_in[20];
    const float* ln_mask_b  = (const float*)d_in[21];
    const float* protos     = (const float*)d_in[22];

    const size_t PLANEH = (size_t)NKG_ACT * GPIX * 8;    // 15,040,512 halves
    const size_t W3SZ   = (size_t)G3 * MDIM * 8;         // 5,013,504
    const size_t W1SZ   = (size_t)G1 * MDIM * 8;         // 589,824

    f16* Xhi  = (f16*)d_ws;
    f16* Xlo  = Xhi + PLANEH;
    f16* Yhi  = Xlo + PLANEH;
    f16* Ylo  = Yhi + PLANEH;
    f16* W3h  = Ylo + PLANEH;
    f16* W3l  = W3h + W3SZ;
    f16* W1ah = W3l + W3SZ;
    f16* W1al = W1ah + W1SZ;
    f16* W1bh = W1al + W1SZ;
    f16* W1bl = W1bh + W1SZ;
    float* alphas = (float*)(W1bl + W1SZ);
    float* betas  = alphas + 3 * MDIM;
    float* protoN = betas + 3 * MDIM;

    prep_kernel<<<21, 256, 0, stream>>>(cls_b, cls_bn_g, cls_bn_b, cls_bn_rm, cls_bn_rv,
                                        proj_b1, proj_bn_g, proj_bn_b, proj_bn_rm, proj_bn_rv,
                                        proj_b2, protos, alphas, betas, protoN);
    {
        int total = G3 * MDIM + 2 * G1 * MDIM;
        wtrans_kernel<<<(total + 255) / 256, 256, 0, stream>>>(cls_w, proj_w1, proj_w2,
                                                               W3h, W3l, W1ah, W1al, W1bh, W1bl);
    }
    {
        int total = 90 * GPIX;
        upsample_kernel<<<(total + 255) / 256, 256, 0, stream>>>(feat1, feat2, feat3, feat4,
                                                                 Xhi, Xlo);
    }

    const size_t GOFF = (size_t)GUARD * 8;
    const int NBLK = 912;             // 8 XCD bands x 114 (19 ncols x 6 m-tiles); 6 no-op tails
    mfma_gemm<405, 1><<<NBLK, 256, 0, stream>>>(W3h, W3l, Xhi + GOFF, Xlo + GOFF,
                                                Yhi + GOFF, Ylo + GOFF,
                                                alphas, betas, 1);
    mfma_gemm<45, 0><<<NBLK, 256, 0, stream>>>(W1ah, W1al, Yhi + GOFF, Ylo + GOFF,
                                               Xhi + GOFF, Xlo + GOFF,
                                               alphas + MDIM, betas + MDIM, 1);
    mfma_gemm<45, 0><<<NBLK, 256, 0, stream>>>(W1bh, W1bl, Xhi + GOFF, Xlo + GOFF,
                                               Yhi + GOFF, Ylo + GOFF,
                                               alphas + 2 * MDIM, betas + 2 * MDIM, 0);

    head_kernel<<<288, 64, 0, stream>>>(Yhi + GOFF, Ylo + GOFF,
                                        ln_feat_g, ln_feat_b, protoN,
                                        ln_mask_g, ln_mask_b, (float*)d_out);
}

// Round 11
// 985.310 us; speedup vs baseline: 1.1806x; 1.1806x over previous
//
#include <hip/hip_runtime.h>
#include <float.h>

#define WDIM 96
#define HW   9216
#define PH   98
#define IMG  (PH*PH)            // 9604
#define NPIXP (2*IMG)           // 19208 real padded pixels
#define NPIX 19328              // 151*128 compute pixels
#define GUARD 128
#define GPIX (NPIX + 2*GUARD)   // 19584
#define NKG_ACT 96              // kg planes per activation buffer (768/8)
#define MDIM 768                // padded cout
#define G3 816                  // conv3x3 kg rows (9*90=810, padded for prefetch overrun)
#define G1 96                   // 1x1 kg rows (90 real, padded for prefetch overrun)

typedef _Float16 f16;
typedef f16  f16x8 __attribute__((ext_vector_type(8)));
typedef f16  f16x4 __attribute__((ext_vector_type(4)));
typedef float f32x4 __attribute__((ext_vector_type(4)));

// ---------------- prep: fold bias+BN into alpha/beta (padded to 768); l2-normalize protos ----
__global__ void prep_kernel(
    const float* __restrict__ cls_b,
    const float* __restrict__ g0, const float* __restrict__ b0,
    const float* __restrict__ rm0, const float* __restrict__ rv0,
    const float* __restrict__ p1b,
    const float* __restrict__ g1, const float* __restrict__ b1,
    const float* __restrict__ rm1, const float* __restrict__ rv1,
    const float* __restrict__ p2b,
    const float* __restrict__ protos,
    float* __restrict__ alpha, float* __restrict__ beta,
    float* __restrict__ protoN)
{
    __shared__ float red[4];
    if (blockIdx.x == 0) {
        for (int i = threadIdx.x; i < MDIM; i += blockDim.x) {
            if (i < 720) {
                float s0 = g0[i] * rsqrtf(rv0[i] + 1e-5f);
                alpha[i] = s0;
                beta[i]  = (cls_b[i] - rm0[i]) * s0 + b0[i];
                float s1 = g1[i] * rsqrtf(rv1[i] + 1e-5f);
                alpha[MDIM + i] = s1;
                beta[MDIM + i]  = (p1b[i] - rm1[i]) * s1 + b1[i];
                alpha[2*MDIM + i] = 1.0f;
                beta[2*MDIM + i]  = p2b[i];
            } else {
                alpha[i] = 0.f; beta[i] = 0.f;
                alpha[MDIM + i] = 0.f; beta[MDIM + i] = 0.f;
                alpha[2*MDIM + i] = 0.f; beta[2*MDIM + i] = 0.f;
            }
        }
    } else {
        int row = blockIdx.x - 1;              // 0..19
        const float* src = protos + row * 720;
        float s = 0.f;
        for (int i = threadIdx.x; i < 720; i += blockDim.x) { float v = src[i]; s += v * v; }
        #pragma unroll
        for (int off = 32; off > 0; off >>= 1) s += __shfl_down(s, off);
        int wave = threadIdx.x >> 6, lane = threadIdx.x & 63;
        if (lane == 0) red[wave] = s;
        __syncthreads();
        float tot = red[0] + red[1] + red[2] + red[3];
        float rn = 1.0f / fmaxf(sqrtf(tot), 1e-12f);
        for (int i = threadIdx.x; i < 720; i += blockDim.x)
            protoN[row * 720 + i] = src[i] * rn;
    }
}

// ---------------- weight transform: OIHW -> split-fp16 K8-packed [kg][cout 768][8] ----------
// conv3x3 K-order is kgl-MAJOR, shift-minor: g = kgl*9 + s (matches mfma_gemm).
__global__ void wtrans_kernel(const float* __restrict__ w3,
                              const float* __restrict__ w1a,
                              const float* __restrict__ w1b,
                              f16* __restrict__ W3h, f16* __restrict__ W3l,
                              f16* __restrict__ W1ah, f16* __restrict__ W1al,
                              f16* __restrict__ W1bh, f16* __restrict__ W1bl)
{
    int tid = blockIdx.x * blockDim.x + threadIdx.x;
    const int N3 = G3 * MDIM;
    const int N1 = G1 * MDIM;
    const float* src; f16 *dh, *dl; int g, o, which;
    if (tid < N3)              { g = tid / MDIM; o = tid - g * MDIM; src = w3;  dh = W3h;  dl = W3l;  which = 0; }
    else if (tid < N3 + N1)    { int u = tid - N3;      g = u / MDIM; o = u - g * MDIM; src = w1a; dh = W1ah; dl = W1al; which = 1; }
    else if (tid < N3 + 2*N1)  { int u = tid - N3 - N1; g = u / MDIM; o = u - g * MDIM; src = w1b; dh = W1bh; dl = W1bl; which = 1; }
    else return;

    float v[8];
    #pragma unroll
    for (int j = 0; j < 8; ++j) v[j] = 0.f;
    if (which == 0) {
        if (g < 810 && o < 720) {
            int kgl = g / 9; int s = g - kgl * 9; int cin0 = kgl * 8;
            #pragma unroll
            for (int j = 0; j < 8; ++j)
                v[j] = src[((size_t)o * 720 + cin0 + j) * 9 + s];
        }
    } else {
        if (g < 90 && o < 720) {
            #pragma unroll
            for (int j = 0; j < 8; ++j)
                v[j] = src[(size_t)o * 720 + g * 8 + j];
        }
    }
    f16x8 hv, lv;
    #pragma unroll
    for (int j = 0; j < 8; ++j) {
        f16 h = (f16)v[j];
        hv[j] = h;
        lv[j] = (f16)(v[j] - (float)h);
    }
    size_t off = ((size_t)g * MDIM + o) * 8;
    *(f16x8*)(dh + off) = hv;
    *(f16x8*)(dl + off) = lv;
}

// ---------------- upsample+concat -> split-fp16 K8-packed padded-image planes ---------------
__global__ void upsample_kernel(const float* __restrict__ f1,
                                const float* __restrict__ f2,
                                const float* __restrict__ f3,
                                const float* __restrict__ f4,
                                f16* __restrict__ Xhi, f16* __restrict__ Xlo)
{
    int tid = blockIdx.x * blockDim.x + threadIdx.x;
    if (tid >= 90 * GPIX) return;
    int kg = tid / GPIX;
    int gp = tid - kg * GPIX;
    int p  = gp - GUARD;
    float v[8];
    #pragma unroll
    for (int j = 0; j < 8; ++j) v[j] = 0.f;
    if (p >= 0 && p < NPIXP) {
        int b = p / IMG; int rem = p - b * IMG;
        int y = rem / PH; int x = rem - y * PH;
        if (y >= 1 && y <= 96 && x >= 1 && x <= 96) {
            int oy = y - 1, ox = x - 1;
            int c0 = kg * 8;
            if (c0 < 48) {
                #pragma unroll
                for (int j = 0; j < 8; ++j)
                    v[j] = f1[((size_t)(b * 48 + c0 + j)) * HW + oy * 96 + ox];
            } else {
                const float* src; int Cs, Hs, cb;
                if (c0 < 144)      { src = f2; Cs = 96;  Hs = 48; cb = c0 - 48; }
                else if (c0 < 336) { src = f3; Cs = 192; Hs = 24; cb = c0 - 144; }
                else               { src = f4; Cs = 384; Hs = 12; cb = c0 - 336; }
                float scale = (float)(Hs - 1) / 95.0f;
                float yf = oy * scale, xf = ox * scale;
                int y0 = (int)yf, x0 = (int)xf;
                float wy = yf - y0, wx = xf - x0;
                int y1 = min(y0 + 1, Hs - 1), x1 = min(x0 + 1, Hs - 1);
                #pragma unroll
                for (int j = 0; j < 8; ++j) {
                    const float* sb = src + (size_t)(b * Cs + cb + j) * Hs * Hs;
                    float v00 = sb[y0 * Hs + x0], v01 = sb[y0 * Hs + x1];
                    float v10 = sb[y1 * Hs + x0], v11 = sb[y1 * Hs + x1];
                    float r0 = v00 * (1.f - wy) + v10 * wy;
                    float r1 = v01 * (1.f - wy) + v11 * wy;
                    v[j] = r0 * (1.f - wx) + r1 * wx;
                }
            }
        }
    }
    f16x8 hv, lv;
    #pragma unroll
    for (int j = 0; j < 8; ++j) {
        f16 h = (f16)v[j];
        hv[j] = h;
        lv[j] = (f16)(v[j] - (float)h);
    }
    size_t off = (size_t)tid * 8;
    *(f16x8*)(Xhi + off) = hv;
    *(f16x8*)(Xlo + off) = lv;
}

// ---------------- split-fp16 MFMA implicit-GEMM conv: barrier-free + B-reg prefetch ----------
// Round-9 structure (16x16x32, no LDS, no __syncthreads) + 1-deep register prefetch of the
// B fragments: B(step+1)'s 8 loads are issued BEFORE step's MFMAs, so their L2/L3 latency is
// covered by the ~931-cyc MFMA phase. A stays load-on-use (L1/L2-hot: shared by all column-
// blocks on the XCD). Regs: 64 acc + 32 Bcur + 32 Bnxt + 32 A + addr ~ 172 (cap ~170 at
// (256,3)) — WRITE_SIZE is the spill tripwire.
template<int NSTEP, int CONV3>
__global__ __launch_bounds__(256, 3)
void mfma_gemm(const f16* __restrict__ Whi, const f16* __restrict__ Wlo,
               const f16* __restrict__ Bhi_, const f16* __restrict__ Blo_,
               f16* __restrict__ Ohi, f16* __restrict__ Olo,
               const float* __restrict__ alpha, const float* __restrict__ beta,
               int relu)
{
    const int l = blockIdx.x;
    const int xcd = l & 7;
    const int j0 = l >> 3;                // 0..113
    const int ncol = xcd * 19 + j0 / 6;   // 19 n-columns per XCD band
    if (ncol >= 151) return;
    const int m0 = (j0 % 6) * 128;
    const int n0 = ncol * 128;

    const int t = threadIdx.x;
    const int lane = t & 63, wid = t >> 6;
    const int wm = wid >> 1, wn = wid & 1;
    const int quad = lane >> 4, ln = lane & 15;

    f32x4 acc[4][4];
    #pragma unroll
    for (int i = 0; i < 4; ++i)
        #pragma unroll
        for (int j = 0; j < 4; ++j)
            acc[i][j] = (f32x4){0.f, 0.f, 0.f, 0.f};

    // A fragment base: row m = m0 + wm*64 + mt*16 + ln, k-group = 4*step + quad
    const int arow = m0 + wm * 64 + ln;
    const f16* Ah0 = Whi + ((size_t)quad * MDIM + arow) * 8;
    const f16* Al0 = Wlo + ((size_t)quad * MDIM + arow) * 8;
    const size_t astep = (size_t)4 * MDIM * 8;

    // B fragment base column: n0 + wn*64 + nt*16 + ln
    const int bcol = n0 + wn * 64 + ln;

    auto brow_of = [&](int step) -> long long {
        const int g = step * 4 + quad;
        if (CONV3) {
            int gc = min(g, 809);
            int kgl = gc / 9;
            int s = gc - kgl * 9;
            int d = (s / 3 - 1) * PH + (s % 3 - 1);
            return (long long)kgl * GPIX + d;
        }
        return (long long)min(g, G1 - 1) * GPIX;
    };

    // prologue: load B fragments for step 0
    f16x8 bcur[8], bnxt[8];
    {
        const long long brow = brow_of(0);
        const f16* bh = Bhi_ + (brow + bcol) * 8;
        const f16* bl = Blo_ + (brow + bcol) * 8;
        #pragma unroll
        for (int nt = 0; nt < 4; ++nt) {
            bcur[nt]     = *(const f16x8*)(bh + nt * 128);
            bcur[nt + 4] = *(const f16x8*)(bl + nt * 128);
        }
    }

    for (int step = 0; step < NSTEP; ++step) {
        // prefetch B(step+1) — consumed next iteration, latency hidden behind MFMAs
        {
            const long long brow = brow_of(step + 1);
            const f16* bh = Bhi_ + (brow + bcol) * 8;
            const f16* bl = Blo_ + (brow + bcol) * 8;
            #pragma unroll
            for (int nt = 0; nt < 4; ++nt) {
                bnxt[nt]     = *(const f16x8*)(bh + nt * 128);
                bnxt[nt + 4] = *(const f16x8*)(bl + nt * 128);
            }
        }
        // A load-on-use (L1/L2-hot)
        const f16* Ah = Ah0 + (size_t)step * astep;
        const f16* Al = Al0 + (size_t)step * astep;
        f16x8 av[8];
        #pragma unroll
        for (int mt = 0; mt < 4; ++mt) {
            av[mt]     = *(const f16x8*)(Ah + mt * 128);
            av[mt + 4] = *(const f16x8*)(Al + mt * 128);
        }
        // split-fp16 MFMA: hh + hl + lh
        #pragma unroll
        for (int mt = 0; mt < 4; ++mt)
            #pragma unroll
            for (int nt = 0; nt < 4; ++nt) {
                acc[mt][nt] = __builtin_amdgcn_mfma_f32_16x16x32_f16(av[mt],     bcur[nt],     acc[mt][nt], 0, 0, 0);
                acc[mt][nt] = __builtin_amdgcn_mfma_f32_16x16x32_f16(av[mt],     bcur[nt + 4], acc[mt][nt], 0, 0, 0);
                acc[mt][nt] = __builtin_amdgcn_mfma_f32_16x16x32_f16(av[mt + 4], bcur[nt],     acc[mt][nt], 0, 0, 0);
            }
        #pragma unroll
        for (int i = 0; i < 8; ++i) bcur[i] = bnxt[i];
    }

    // ---- epilogue ----
    #pragma unroll
    for (int mt = 0; mt < 4; ++mt) {
        const int rowb = m0 + wm * 64 + mt * 16 + quad * 4;   // cout of reg 0
        const float4 a4 = *(const float4*)(alpha + rowb);
        const float4 b4 = *(const float4*)(beta + rowb);
        const size_t kg = rowb >> 3;
        const int sub = rowb & 7;                             // 0 or 4
        #pragma unroll
        for (int nt = 0; nt < 4; ++nt) {
            const int P = n0 + wn * 64 + nt * 16 + ln;
            float v0 = acc[mt][nt][0] * a4.x + b4.x;
            float v1 = acc[mt][nt][1] * a4.y + b4.y;
            float v2 = acc[mt][nt][2] * a4.z + b4.z;
            float v3 = acc[mt][nt][3] * a4.w + b4.w;
            if (relu) {
                v0 = fmaxf(v0, 0.f); v1 = fmaxf(v1, 0.f);
                v2 = fmaxf(v2, 0.f); v3 = fmaxf(v3, 0.f);
            }
            f16 h0 = (f16)v0, h1 = (f16)v1, h2 = (f16)v2, h3 = (f16)v3;
            f16x4 hv = {h0, h1, h2, h3};
            f16x4 lv = {(f16)(v0 - (float)h0), (f16)(v1 - (float)h1),
                        (f16)(v2 - (float)h2), (f16)(v3 - (float)h3)};
            size_t o = (kg * GPIX + P) * 8 + sub;
            *(f16x4*)(Ohi + o) = hv;
            *(f16x4*)(Olo + o) = lv;
        }
    }
}

// ---------------- head: LN(720) -> l2norm -> proto dots -> max -> LN(2) ----------------------
__global__ __launch_bounds__(64)
void head_kernel(const f16* __restrict__ Yhi, const f16* __restrict__ Ylo,  // at GUARD
                 const float* __restrict__ lng, const float* __restrict__ lnb,
                 const float* __restrict__ protoN,
                 const float* __restrict__ lmg, const float* __restrict__ lmb,
                 float* __restrict__ out)
{
    int p = blockIdx.x * blockDim.x + threadIdx.x;   // 0..18431
    int b = p / HW; int r = p - b * HW;
    int y = r / 96; int x = r - y * 96;
    size_t P = (size_t)b * IMG + (y + 1) * PH + (x + 1);

    float s1 = 0.f, s2 = 0.f;
    for (int kg = 0; kg < 90; ++kg) {
        f16x8 hv = *(const f16x8*)(Yhi + ((size_t)kg * GPIX + P) * 8);
        f16x8 lv = *(const f16x8*)(Ylo + ((size_t)kg * GPIX + P) * 8);
        #pragma unroll
        for (int j = 0; j < 8; ++j) {
            float v = (float)hv[j] + (float)lv[j];
            s1 += v; s2 += v * v;
        }
    }
    float mu  = s1 * (1.0f / 720.0f);
    float var = s2 * (1.0f / 720.0f) - mu * mu;
    float inv = rsqrtf(var + 1e-5f);

    float dots[20];
    #pragma unroll
    for (int j = 0; j < 20; ++j) dots[j] = 0.f;
    float nrm = 0.f;
    for (int kg = 0; kg < 90; ++kg) {
        f16x8 hv = *(const f16x8*)(Yhi + ((size_t)kg * GPIX + P) * 8);
        f16x8 lv = *(const f16x8*)(Ylo + ((size_t)kg * GPIX + P) * 8);
        #pragma unroll
        for (int j = 0; j < 8; ++j) {
            int c = kg * 8 + j;
            float v = ((float)hv[j] + (float)lv[j] - mu) * inv * lng[c] + lnb[c];
            nrm += v * v;
            #pragma unroll
            for (int k = 0; k < 20; ++k)
                dots[k] = fmaf(v, protoN[k * 720 + c], dots[k]);
        }
    }
    float rn = 1.0f / fmaxf(sqrtf(nrm), 1e-12f);
    float m0v = -FLT_MAX, m1v = -FLT_MAX;
    #pragma unroll
    for (int j = 0; j < 10; ++j) m0v = fmaxf(m0v, dots[j]);
    #pragma unroll
    for (int j = 10; j < 20; ++j) m1v = fmaxf(m1v, dots[j]);
    m0v *= rn; m1v *= rn;
    float mu2 = 0.5f * (m0v + m1v);
    float dv  = m0v - mu2;
    float va  = dv * dv;
    float iv  = rsqrtf(va + 1e-5f);
    float o0 = (m0v - mu2) * iv * lmg[0] + lmb[0];
    float o1 = (m1v - mu2) * iv * lmg[1] + lmb[1];
    out[b * (2 * HW) + r]      = o0;
    out[b * (2 * HW) + HW + r] = o1;
}

extern "C" void kernel_launch(void* const* d_in, const int* in_sizes, int n_in,
                              void* d_out, int out_size, void* d_ws, size_t ws_size,
                              hipStream_t stream)
{
    const float* feat1      = (const float*)d_in[0];
    const float* feat2      = (const float*)d_in[1];
    const float* feat3      = (const float*)d_in[2];
    const float* feat4      = (const float*)d_in[3];
    const float* cls_w      = (const float*)d_in[4];
    const float* cls_b      = (const float*)d_in[5];
    const float* cls_bn_g   = (const float*)d_in[6];
    const float* cls_bn_b   = (const float*)d_in[7];
    const float* cls_bn_rm  = (const float*)d_in[8];
    const float* cls_bn_rv  = (const float*)d_in[9];
    const float* proj_w1    = (const float*)d_in[10];
    const float* proj_b1    = (const float*)d_in[11];
    const float* proj_bn_g  = (const float*)d_in[12];
    const float* proj_bn_b  = (const float*)d_in[13];
    const float* proj_bn_rm = (const float*)d_in[14];
    const float* proj_bn_rv = (const float*)d_in[15];
    const float* proj_w2    = (const float*)d_in[16];
    const float* proj_b2    = (const float*)d_in[17];
    const float* ln_feat_g  = (const float*)d_in[18];
    const float* ln_feat_b  = (const float*)d_in[19];
    const float* ln_mask_g  = (const float*)d_in[20];
    const float* ln_mask_b  = (const float*)d_in[21];
    const float* protos     = (const float*)d_in[22];

    const size_t PLANEH = (size_t)NKG_ACT * GPIX * 8;    // 15,040,512 halves
    const size_t W3SZ   = (size_t)G3 * MDIM * 8;         // 5,013,504
    const size_t W1SZ   = (size_t)G1 * MDIM * 8;         // 589,824

    f16* Xhi  = (f16*)d_ws;
    f16* Xlo  = Xhi + PLANEH;
    f16* Yhi  = Xlo + PLANEH;
    f16* Ylo  = Yhi + PLANEH;
    f16* W3h  = Ylo + PLANEH;
    f16* W3l  = W3h + W3SZ;
    f16* W1ah = W3l + W3SZ;
    f16* W1al = W1ah + W1SZ;
    f16* W1bh = W1al + W1SZ;
    f16* W1bl = W1bh + W1SZ;
    float* alphas = (float*)(W1bl + W1SZ);
    float* betas  = alphas + 3 * MDIM;
    float* protoN = betas + 3 * MDIM;

    prep_kernel<<<21, 256, 0, stream>>>(cls_b, cls_bn_g, cls_bn_b, cls_bn_rm, cls_bn_rv,
                                        proj_b1, proj_bn_g, proj_bn_b, proj_bn_rm, proj_bn_rv,
                                        proj_b2, protos, alphas, betas, protoN);
    {
        int total = G3 * MDIM + 2 * G1 * MDIM;
        wtrans_kernel<<<(total + 255) / 256, 256, 0, stream>>>(cls_w, proj_w1, proj_w2,
                                                               W3h, W3l, W1ah, W1al, W1bh, W1bl);
    }
    {
        int total = 90 * GPIX;
        upsample_kernel<<<(total + 255) / 256, 256, 0, stream>>>(feat1, feat2, feat3, feat4,
                                                                 Xhi, Xlo);
    }

    const size_t GOFF = (size_t)GUARD * 8;
    const int NBLK = 912;             // 8 XCD bands x 114 (19 ncols x 6 m-tiles); 6 no-op tails
    mfma_gemm<203, 1><<<NBLK, 256, 0, stream>>>(W3h, W3l, Xhi + GOFF, Xlo + GOFF,
                                                Yhi + GOFF, Ylo + GOFF,
                                                alphas, betas, 1);
    mfma_gemm<23, 0><<<NBLK, 256, 0, stream>>>(W1ah, W1al, Yhi + GOFF, Ylo + GOFF,
                                               Xhi + GOFF, Xlo + GOFF,
                                               alphas + MDIM, betas + MDIM, 1);
    mfma_gemm<23, 0><<<NBLK, 256, 0, stream>>>(W1bh, W1bl, Xhi + GOFF, Xlo + GOFF,
                                               Yhi + GOFF, Ylo + GOFF,
                                               alphas + 2 * MDIM, betas + 2 * MDIM, 0);

    head_kernel<<<288, 64, 0, stream>>>(Yhi + GOFF, Ylo + GOFF,
                                        ln_feat_g, ln_feat_b, protoN,
                                        ln_mask_g, ln_mask_b, (float*)d_out);
}

// Round 14
// 825.351 us; speedup vs baseline: 1.4094x; 1.1938x over previous
//
#include <hip/hip_runtime.h>
#include <float.h>

#define WDIM 96
#define HW   9216
#define PH   98
#define IMG  (PH*PH)            // 9604
#define NPIXP (2*IMG)           // 19208 real padded pixels
#define NPIX 19328              // 151*128 compute pixels
#define GUARD 128
#define GPIX (NPIX + 2*GUARD)   // 19584
#define NKG_ACT 96              // kg planes per activation buffer (768/8)
#define MDIM 768                // padded cout
#define G3 816                  // conv3x3 kg rows (9*90=810, padded for prefetch overrun)
#define G1 96                   // 1x1 kg rows (90 real, padded for prefetch overrun)

typedef _Float16 f16;
typedef f16  f16x8 __attribute__((ext_vector_type(8)));
typedef f16  f16x4 __attribute__((ext_vector_type(4)));
typedef float f32x4 __attribute__((ext_vector_type(4)));

// ---------------- prep: fold bias+BN into alpha/beta (padded to 768); l2-normalize protos ----
// (round-11 exact: protoN layout [20][720])
__global__ void prep_kernel(
    const float* __restrict__ cls_b,
    const float* __restrict__ g0, const float* __restrict__ b0,
    const float* __restrict__ rm0, const float* __restrict__ rv0,
    const float* __restrict__ p1b,
    const float* __restrict__ g1, const float* __restrict__ b1,
    const float* __restrict__ rm1, const float* __restrict__ rv1,
    const float* __restrict__ p2b,
    const float* __restrict__ protos,
    float* __restrict__ alpha, float* __restrict__ beta,
    float* __restrict__ protoN)
{
    __shared__ float red[4];
    if (blockIdx.x == 0) {
        for (int i = threadIdx.x; i < MDIM; i += blockDim.x) {
            if (i < 720) {
                float s0 = g0[i] * rsqrtf(rv0[i] + 1e-5f);
                alpha[i] = s0;
                beta[i]  = (cls_b[i] - rm0[i]) * s0 + b0[i];
                float s1 = g1[i] * rsqrtf(rv1[i] + 1e-5f);
                alpha[MDIM + i] = s1;
                beta[MDIM + i]  = (p1b[i] - rm1[i]) * s1 + b1[i];
                alpha[2*MDIM + i] = 1.0f;
                beta[2*MDIM + i]  = p2b[i];
            } else {
                alpha[i] = 0.f; beta[i] = 0.f;
                alpha[MDIM + i] = 0.f; beta[MDIM + i] = 0.f;
                alpha[2*MDIM + i] = 0.f; beta[2*MDIM + i] = 0.f;
            }
        }
    } else {
        int row = blockIdx.x - 1;              // 0..19
        const float* src = protos + row * 720;
        float s = 0.f;
        for (int i = threadIdx.x; i < 720; i += blockDim.x) { float v = src[i]; s += v * v; }
        #pragma unroll
        for (int off = 32; off > 0; off >>= 1) s += __shfl_down(s, off);
        int wave = threadIdx.x >> 6, lane = threadIdx.x & 63;
        if (lane == 0) red[wave] = s;
        __syncthreads();
        float tot = red[0] + red[1] + red[2] + red[3];
        float rn = 1.0f / fmaxf(sqrtf(tot), 1e-12f);
        for (int i = threadIdx.x; i < 720; i += blockDim.x)
            protoN[row * 720 + i] = src[i] * rn;
    }
}

// ---------------- weight transform: OIHW -> split-fp16 K8-packed [kg][cout 768][8] ----------
// (round-11 exact) conv3x3 K-order is kgl-MAJOR, shift-minor: g = kgl*9 + s.
__global__ void wtrans_kernel(const float* __restrict__ w3,
                              const float* __restrict__ w1a,
                              const float* __restrict__ w1b,
                              f16* __restrict__ W3h, f16* __restrict__ W3l,
                              f16* __restrict__ W1ah, f16* __restrict__ W1al,
                              f16* __restrict__ W1bh, f16* __restrict__ W1bl)
{
    int tid = blockIdx.x * blockDim.x + threadIdx.x;
    const int N3 = G3 * MDIM;
    const int N1 = G1 * MDIM;
    const float* src; f16 *dh, *dl; int g, o, which;
    if (tid < N3)              { g = tid / MDIM; o = tid - g * MDIM; src = w3;  dh = W3h;  dl = W3l;  which = 0; }
    else if (tid < N3 + N1)    { int u = tid - N3;      g = u / MDIM; o = u - g * MDIM; src = w1a; dh = W1ah; dl = W1al; which = 1; }
    else if (tid < N3 + 2*N1)  { int u = tid - N3 - N1; g = u / MDIM; o = u - g * MDIM; src = w1b; dh = W1bh; dl = W1bl; which = 1; }
    else return;

    float v[8];
    #pragma unroll
    for (int j = 0; j < 8; ++j) v[j] = 0.f;
    if (which == 0) {
        if (g < 810 && o < 720) {
            int kgl = g / 9; int s = g - kgl * 9; int cin0 = kgl * 8;
            #pragma unroll
            for (int j = 0; j < 8; ++j)
                v[j] = src[((size_t)o * 720 + cin0 + j) * 9 + s];
        }
    } else {
        if (g < 90 && o < 720) {
            #pragma unroll
            for (int j = 0; j < 8; ++j)
                v[j] = src[(size_t)o * 720 + g * 8 + j];
        }
    }
    f16x8 hv, lv;
    #pragma unroll
    for (int j = 0; j < 8; ++j) {
        f16 h = (f16)v[j];
        hv[j] = h;
        lv[j] = (f16)(v[j] - (float)h);
    }
    size_t off = ((size_t)g * MDIM + o) * 8;
    *(f16x8*)(dh + off) = hv;
    *(f16x8*)(dl + off) = lv;
}

// ---------------- upsample+concat -> split-fp16 K8-packed padded-image planes ---------------
__global__ void upsample_kernel(const float* __restrict__ f1,
                                const float* __restrict__ f2,
                                const float* __restrict__ f3,
                                const float* __restrict__ f4,
                                f16* __restrict__ Xhi, f16* __restrict__ Xlo)
{
    int tid = blockIdx.x * blockDim.x + threadIdx.x;
    if (tid >= 90 * GPIX) return;
    int kg = tid / GPIX;
    int gp = tid - kg * GPIX;
    int p  = gp - GUARD;
    float v[8];
    #pragma unroll
    for (int j = 0; j < 8; ++j) v[j] = 0.f;
    if (p >= 0 && p < NPIXP) {
        int b = p / IMG; int rem = p - b * IMG;
        int y = rem / PH; int x = rem - y * PH;
        if (y >= 1 && y <= 96 && x >= 1 && x <= 96) {
            int oy = y - 1, ox = x - 1;
            int c0 = kg * 8;
            if (c0 < 48) {
                #pragma unroll
                for (int j = 0; j < 8; ++j)
                    v[j] = f1[((size_t)(b * 48 + c0 + j)) * HW + oy * 96 + ox];
            } else {
                const float* src; int Cs, Hs, cb;
                if (c0 < 144)      { src = f2; Cs = 96;  Hs = 48; cb = c0 - 48; }
                else if (c0 < 336) { src = f3; Cs = 192; Hs = 24; cb = c0 - 144; }
                else               { src = f4; Cs = 384; Hs = 12; cb = c0 - 336; }
                float scale = (float)(Hs - 1) / 95.0f;
                float yf = oy * scale, xf = ox * scale;
                int y0 = (int)yf, x0 = (int)xf;
                float wy = yf - y0, wx = xf - x0;
                int y1 = min(y0 + 1, Hs - 1), x1 = min(x0 + 1, Hs - 1);
                #pragma unroll
                for (int j = 0; j < 8; ++j) {
                    const float* sb = src + (size_t)(b * Cs + cb + j) * Hs * Hs;
                    float v00 = sb[y0 * Hs + x0], v01 = sb[y0 * Hs + x1];
                    float v10 = sb[y1 * Hs + x0], v11 = sb[y1 * Hs + x1];
                    float r0 = v00 * (1.f - wy) + v10 * wy;
                    float r1 = v01 * (1.f - wy) + v11 * wy;
                    v[j] = r0 * (1.f - wx) + r1 * wx;
                }
            }
        }
    }
    f16x8 hv, lv;
    #pragma unroll
    for (int j = 0; j < 8; ++j) {
        f16 h = (f16)v[j];
        hv[j] = h;
        lv[j] = (f16)(v[j] - (float)h);
    }
    size_t off = (size_t)tid * 8;
    *(f16x8*)(Xhi + off) = hv;
    *(f16x8*)(Xlo + off) = lv;
}

// ---------------- split-fp16 MFMA implicit-GEMM conv: barrier-free + B-reg prefetch ----------
// (round-11 winner, unchanged — the control)
template<int NSTEP, int CONV3>
__global__ __launch_bounds__(256, 3)
void mfma_gemm(const f16* __restrict__ Whi, const f16* __restrict__ Wlo,
               const f16* __restrict__ Bhi_, const f16* __restrict__ Blo_,
               f16* __restrict__ Ohi, f16* __restrict__ Olo,
               const float* __restrict__ alpha, const float* __restrict__ beta,
               int relu)
{
    const int l = blockIdx.x;
    const int xcd = l & 7;
    const int j0 = l >> 3;                // 0..113
    const int ncol = xcd * 19 + j0 / 6;   // 19 n-columns per XCD band
    if (ncol >= 151) return;
    const int m0 = (j0 % 6) * 128;
    const int n0 = ncol * 128;

    const int t = threadIdx.x;
    const int lane = t & 63, wid = t >> 6;
    const int wm = wid >> 1, wn = wid & 1;
    const int quad = lane >> 4, ln = lane & 15;

    f32x4 acc[4][4];
    #pragma unroll
    for (int i = 0; i < 4; ++i)
        #pragma unroll
        for (int j = 0; j < 4; ++j)
            acc[i][j] = (f32x4){0.f, 0.f, 0.f, 0.f};

    const int arow = m0 + wm * 64 + ln;
    const f16* Ah0 = Whi + ((size_t)quad * MDIM + arow) * 8;
    const f16* Al0 = Wlo + ((size_t)quad * MDIM + arow) * 8;
    const size_t astep = (size_t)4 * MDIM * 8;

    const int bcol = n0 + wn * 64 + ln;

    auto brow_of = [&](int step) -> long long {
        const int g = step * 4 + quad;
        if (CONV3) {
            int gc = min(g, 809);
            int kgl = gc / 9;
            int s = gc - kgl * 9;
            int d = (s / 3 - 1) * PH + (s % 3 - 1);
            return (long long)kgl * GPIX + d;
        }
        return (long long)min(g, G1 - 1) * GPIX;
    };

    f16x8 bcur[8], bnxt[8];
    {
        const long long brow = brow_of(0);
        const f16* bh = Bhi_ + (brow + bcol) * 8;
        const f16* bl = Blo_ + (brow + bcol) * 8;
        #pragma unroll
        for (int nt = 0; nt < 4; ++nt) {
            bcur[nt]     = *(const f16x8*)(bh + nt * 128);
            bcur[nt + 4] = *(const f16x8*)(bl + nt * 128);
        }
    }

    for (int step = 0; step < NSTEP; ++step) {
        {
            const long long brow = brow_of(step + 1);
            const f16* bh = Bhi_ + (brow + bcol) * 8;
            const f16* bl = Blo_ + (brow + bcol) * 8;
            #pragma unroll
            for (int nt = 0; nt < 4; ++nt) {
                bnxt[nt]     = *(const f16x8*)(bh + nt * 128);
                bnxt[nt + 4] = *(const f16x8*)(bl + nt * 128);
            }
        }
        const f16* Ah = Ah0 + (size_t)step * astep;
        const f16* Al = Al0 + (size_t)step * astep;
        f16x8 av[8];
        #pragma unroll
        for (int mt = 0; mt < 4; ++mt) {
            av[mt]     = *(const f16x8*)(Ah + mt * 128);
            av[mt + 4] = *(const f16x8*)(Al + mt * 128);
        }
        #pragma unroll
        for (int mt = 0; mt < 4; ++mt)
            #pragma unroll
            for (int nt = 0; nt < 4; ++nt) {
                acc[mt][nt] = __builtin_amdgcn_mfma_f32_16x16x32_f16(av[mt],     bcur[nt],     acc[mt][nt], 0, 0, 0);
                acc[mt][nt] = __builtin_amdgcn_mfma_f32_16x16x32_f16(av[mt],     bcur[nt + 4], acc[mt][nt], 0, 0, 0);
                acc[mt][nt] = __builtin_amdgcn_mfma_f32_16x16x32_f16(av[mt + 4], bcur[nt],     acc[mt][nt], 0, 0, 0);
            }
        #pragma unroll
        for (int i = 0; i < 8; ++i) bcur[i] = bnxt[i];
    }

    #pragma unroll
    for (int mt = 0; mt < 4; ++mt) {
        const int rowb = m0 + wm * 64 + mt * 16 + quad * 4;
        const float4 a4 = *(const float4*)(alpha + rowb);
        const float4 b4 = *(const float4*)(beta + rowb);
        const size_t kg = rowb >> 3;
        const int sub = rowb & 7;
        #pragma unroll
        for (int nt = 0; nt < 4; ++nt) {
            const int P = n0 + wn * 64 + nt * 16 + ln;
            float v0 = acc[mt][nt][0] * a4.x + b4.x;
            float v1 = acc[mt][nt][1] * a4.y + b4.y;
            float v2 = acc[mt][nt][2] * a4.z + b4.z;
            float v3 = acc[mt][nt][3] * a4.w + b4.w;
            if (relu) {
                v0 = fmaxf(v0, 0.f); v1 = fmaxf(v1, 0.f);
                v2 = fmaxf(v2, 0.f); v3 = fmaxf(v3, 0.f);
            }
            f16 h0 = (f16)v0, h1 = (f16)v1, h2 = (f16)v2, h3 = (f16)v3;
            f16x4 hv = {h0, h1, h2, h3};
            f16x4 lv = {(f16)(v0 - (float)h0), (f16)(v1 - (float)h1),
                        (f16)(v2 - (float)h2), (f16)(v3 - (float)h3)};
            size_t o = (kg * GPIX + P) * 8 + sub;
            *(f16x4*)(Ohi + o) = hv;
            *(f16x4*)(Olo + o) = lv;
        }
    }
}

// ---------------- head v2: 16 lanes/pixel, single pass over Y (values held in registers) -----
// LN(720) -> l2norm -> proto dots (protoN [20][720], round-11 layout) -> max -> LN(2).
__global__ __launch_bounds__(256)
void head_kernel(const f16* __restrict__ Yhi, const f16* __restrict__ Ylo,  // at GUARD
                 const float* __restrict__ lng, const float* __restrict__ lnb,
                 const float* __restrict__ protoN,
                 const float* __restrict__ lmg, const float* __restrict__ lmb,
                 float* __restrict__ out)
{
    const int t = threadIdx.x;
    const int wv = t >> 6, lane = t & 63;
    const int pw = lane >> 4, sub = lane & 15;
    const int p = blockIdx.x * 16 + wv * 4 + pw;     // 0..18431
    const int b = p / HW; const int r = p - b * HW;
    const int y = r / 96; const int x = r - y * 96;
    const size_t P = (size_t)b * IMG + (y + 1) * PH + (x + 1);

    // lane sub handles kg = sub + 16*k, k = 0..5 (kg < 90)
    f16x8 xh[6], xl[6];
    float s1 = 0.f, s2 = 0.f;
    #pragma unroll
    for (int k = 0; k < 6; ++k) {
        int kg = sub + 16 * k;
        if (kg < 90) {
            xh[k] = *(const f16x8*)(Yhi + ((size_t)kg * GPIX + P) * 8);
            xl[k] = *(const f16x8*)(Ylo + ((size_t)kg * GPIX + P) * 8);
            #pragma unroll
            for (int j = 0; j < 8; ++j) {
                float v = (float)xh[k][j] + (float)xl[k][j];
                s1 += v; s2 += v * v;
            }
        }
    }
    #pragma unroll
    for (int m = 1; m < 16; m <<= 1) {
        s1 += __shfl_xor(s1, m);
        s2 += __shfl_xor(s2, m);
    }
    float mu  = s1 * (1.0f / 720.0f);
    float var = s2 * (1.0f / 720.0f) - mu * mu;
    float inv = rsqrtf(var + 1e-5f);

    float dots[20];
    #pragma unroll
    for (int q = 0; q < 20; ++q) dots[q] = 0.f;
    float nrm = 0.f;
    #pragma unroll
    for (int k = 0; k < 6; ++k) {
        int kg = sub + 16 * k;
        if (kg < 90) {
            const int c0 = kg * 8;
            #pragma unroll
            for (int j = 0; j < 8; ++j) {
                const int c = c0 + j;
                float v = ((float)xh[k][j] + (float)xl[k][j] - mu) * inv * lng[c] + lnb[c];
                nrm += v * v;
                #pragma unroll
                for (int q = 0; q < 20; ++q)
                    dots[q] = fmaf(v, protoN[q * 720 + c], dots[q]);
            }
        }
    }
    #pragma unroll
    for (int m = 1; m < 16; m <<= 1) {
        nrm += __shfl_xor(nrm, m);
        #pragma unroll
        for (int q = 0; q < 20; ++q) dots[q] += __shfl_xor(dots[q], m);
    }

    if (sub == 0) {
        float rn = 1.0f / fmaxf(sqrtf(nrm), 1e-12f);
        float m0v = -FLT_MAX, m1v = -FLT_MAX;
        #pragma unroll
        for (int q = 0; q < 10; ++q) m0v = fmaxf(m0v, dots[q]);
        #pragma unroll
        for (int q = 10; q < 20; ++q) m1v = fmaxf(m1v, dots[q]);
        m0v *= rn; m1v *= rn;
        float mu2 = 0.5f * (m0v + m1v);
        float dv  = m0v - mu2;
        float va  = dv * dv;
        float iv  = rsqrtf(va + 1e-5f);
        float o0 = (m0v - mu2) * iv * lmg[0] + lmb[0];
        float o1 = (m1v - mu2) * iv * lmg[1] + lmb[1];
        out[b * (2 * HW) + r]      = o0;
        out[b * (2 * HW) + HW + r] = o1;
    }
}

extern "C" void kernel_launch(void* const* d_in, const int* in_sizes, int n_in,
                              void* d_out, int out_size, void* d_ws, size_t ws_size,
                              hipStream_t stream)
{
    const float* feat1      = (const float*)d_in[0];
    const float* feat2      = (const float*)d_in[1];
    const float* feat3      = (const float*)d_in[2];
    const float* feat4      = (const float*)d_in[3];
    const float* cls_w      = (const float*)d_in[4];
    const float* cls_b      = (const float*)d_in[5];
    const float* cls_bn_g   = (const float*)d_in[6];
    const float* cls_bn_b   = (const float*)d_in[7];
    const float* cls_bn_rm  = (const float*)d_in[8];
    const float* cls_bn_rv  = (const float*)d_in[9];
    const float* proj_w1    = (const float*)d_in[10];
    const float* proj_b1    = (const float*)d_in[11];
    const float* proj_bn_g  = (const float*)d_in[12];
    const float* proj_bn_b  = (const float*)d_in[13];
    const float* proj_bn_rm = (const float*)d_in[14];
    const float* proj_bn_rv = (const float*)d_in[15];
    const float* proj_w2    = (const float*)d_in[16];
    const float* proj_b2    = (const float*)d_in[17];
    const float* ln_feat_g  = (const float*)d_in[18];
    const float* ln_feat_b  = (const float*)d_in[19];
    const float* ln_mask_g  = (const float*)d_in[20];
    const float* ln_mask_b  = (const float*)d_in[21];
    const float* protos     = (const float*)d_in[22];

    const size_t PLANEH = (size_t)NKG_ACT * GPIX * 8;    // 15,040,512 halves
    const size_t W3SZ   = (size_t)G3 * MDIM * 8;         // 5,013,504
    const size_t W1SZ   = (size_t)G1 * MDIM * 8;         // 589,824

    f16* Xhi  = (f16*)d_ws;
    f16* Xlo  = Xhi + PLANEH;
    f16* Yhi  = Xlo + PLANEH;
    f16* Ylo  = Yhi + PLANEH;
    f16* W3h  = Ylo + PLANEH;
    f16* W3l  = W3h + W3SZ;
    f16* W1ah = W3l + W3SZ;
    f16* W1al = W1ah + W1SZ;
    f16* W1bh = W1al + W1SZ;
    f16* W1bl = W1bh + W1SZ;
    float* alphas = (float*)(W1bl + W1SZ);
    float* betas  = alphas + 3 * MDIM;
    float* protoN = betas + 3 * MDIM;                    // [20][720]

    prep_kernel<<<21, 256, 0, stream>>>(cls_b, cls_bn_g, cls_bn_b, cls_bn_rm, cls_bn_rv,
                                        proj_b1, proj_bn_g, proj_bn_b, proj_bn_rm, proj_bn_rv,
                                        proj_b2, protos, alphas, betas, protoN);
    {
        int total = G3 * MDIM + 2 * G1 * MDIM;
        wtrans_kernel<<<(total + 255) / 256, 256, 0, stream>>>(cls_w, proj_w1, proj_w2,
                                                               W3h, W3l, W1ah, W1al, W1bh, W1bl);
    }
    {
        int total = 90 * GPIX;
        upsample_kernel<<<(total + 255) / 256, 256, 0, stream>>>(feat1, feat2, feat3, feat4,
                                                                 Xhi, Xlo);
    }

    const size_t GOFF = (size_t)GUARD * 8;
    const int NBLK = 912;             // 8 XCD bands x 114 (19 ncols x 6 m-tiles); 6 no-op tails
    mfma_gemm<203, 1><<<NBLK, 256, 0, stream>>>(W3h, W3l, Xhi + GOFF, Xlo + GOFF,
                                                Yhi + GOFF, Ylo + GOFF,
                                                alphas, betas, 1);
    mfma_gemm<23, 0><<<NBLK, 256, 0, stream>>>(W1ah, W1al, Yhi + GOFF, Ylo + GOFF,
                                               Xhi + GOFF, Xlo + GOFF,
                                               alphas + MDIM, betas + MDIM, 1);
    mfma_gemm<23, 0><<<NBLK, 256, 0, stream>>>(W1bh, W1bl, Xhi + GOFF, Xlo + GOFF,
                                               Yhi + GOFF, Ylo + GOFF,
                                               alphas + 2 * MDIM, betas + 2 * MDIM, 0);

    head_kernel<<<HW * 2 / 16, 256, 0, stream>>>(Yhi + GOFF, Ylo + GOFF,
                                                 ln_feat_g, ln_feat_b, protoN,
                                                 ln_mask_g, ln_mask_b, (float*)d_out);
}

// Round 15
// 801.744 us; speedup vs baseline: 1.4509x; 1.0294x over previous
//
#include <hip/hip_runtime.h>
#include <float.h>

#define WDIM 96
#define HW   9216
#define PH   98
#define IMG  (PH*PH)            // 9604
#define NPIXP (2*IMG)           // 19208 real padded pixels
#define NPIX 19328              // 151*128 compute pixels
#define GUARD 128
#define GPIX (NPIX + 2*GUARD)   // 19584
#define NKG_ACT 96              // kg planes per activation buffer (768/8)
#define MDIM 768                // padded cout
#define G3 816                  // conv3x3 kg rows (9*90=810, padded for prefetch overrun)
#define G1 96                   // 1x1 kg rows (90 real, padded for prefetch overrun)

typedef _Float16 f16;
typedef f16  f16x8 __attribute__((ext_vector_type(8)));
typedef f16  f16x4 __attribute__((ext_vector_type(4)));
typedef float f32x4 __attribute__((ext_vector_type(4)));

// ---------------- prep: fold bias+BN into alpha/beta (padded to 768); l2-normalize protos ----
// (round-11 exact: protoN layout [20][720])
__global__ void prep_kernel(
    const float* __restrict__ cls_b,
    const float* __restrict__ g0, const float* __restrict__ b0,
    const float* __restrict__ rm0, const float* __restrict__ rv0,
    const float* __restrict__ p1b,
    const float* __restrict__ g1, const float* __restrict__ b1,
    const float* __restrict__ rm1, const float* __restrict__ rv1,
    const float* __restrict__ p2b,
    const float* __restrict__ protos,
    float* __restrict__ alpha, float* __restrict__ beta,
    float* __restrict__ protoN)
{
    __shared__ float red[4];
    if (blockIdx.x == 0) {
        for (int i = threadIdx.x; i < MDIM; i += blockDim.x) {
            if (i < 720) {
                float s0 = g0[i] * rsqrtf(rv0[i] + 1e-5f);
                alpha[i] = s0;
                beta[i]  = (cls_b[i] - rm0[i]) * s0 + b0[i];
                float s1 = g1[i] * rsqrtf(rv1[i] + 1e-5f);
                alpha[MDIM + i] = s1;
                beta[MDIM + i]  = (p1b[i] - rm1[i]) * s1 + b1[i];
                alpha[2*MDIM + i] = 1.0f;
                beta[2*MDIM + i]  = p2b[i];
            } else {
                alpha[i] = 0.f; beta[i] = 0.f;
                alpha[MDIM + i] = 0.f; beta[MDIM + i] = 0.f;
                alpha[2*MDIM + i] = 0.f; beta[2*MDIM + i] = 0.f;
            }
        }
    } else {
        int row = blockIdx.x - 1;              // 0..19
        const float* src = protos + row * 720;
        float s = 0.f;
        for (int i = threadIdx.x; i < 720; i += blockDim.x) { float v = src[i]; s += v * v; }
        #pragma unroll
        for (int off = 32; off > 0; off >>= 1) s += __shfl_down(s, off);
        int wave = threadIdx.x >> 6, lane = threadIdx.x & 63;
        if (lane == 0) red[wave] = s;
        __syncthreads();
        float tot = red[0] + red[1] + red[2] + red[3];
        float rn = 1.0f / fmaxf(sqrtf(tot), 1e-12f);
        for (int i = threadIdx.x; i < 720; i += blockDim.x)
            protoN[row * 720 + i] = src[i] * rn;
    }
}

// ---------------- w3 transform: dense per-thread chunk transpose (no LDS) -------------------
// thread = (kgl, o): reads w3[o][kgl*8 .. kgl*8+8)[0..9) = 72 CONTIGUOUS floats (288 B, full
// line utilization), emits 9 shifts x 2 planes of f16x8 at [(kgl*9+s)*768+o] — consecutive o
// -> coalesced 16 B writes. kgl==90 zero-fills pad rows g in [810, G3).
__global__ __launch_bounds__(256)
void w3trans_kernel(const float* __restrict__ w3,
                    f16* __restrict__ W3h, f16* __restrict__ W3l)
{
    int tid = blockIdx.x * blockDim.x + threadIdx.x;
    int kgl = tid / MDIM;
    int o   = tid - kgl * MDIM;
    if (kgl > 90) return;

    if (kgl == 90) {
        // zero pad rows g in [810, G3)
        f16x8 z = {0, 0, 0, 0, 0, 0, 0, 0};
        for (int g = 810; g < G3; ++g) {
            size_t off = ((size_t)g * MDIM + o) * 8;
            *(f16x8*)(W3h + off) = z;
            *(f16x8*)(W3l + off) = z;
        }
        return;
    }

    float buf[72];
    if (o < 720) {
        const float* src = w3 + (size_t)o * 6480 + kgl * 72;
        #pragma unroll
        for (int c = 0; c < 72; ++c) buf[c] = src[c];
    } else {
        #pragma unroll
        for (int c = 0; c < 72; ++c) buf[c] = 0.f;
    }

    #pragma unroll
    for (int s = 0; s < 9; ++s) {
        f16x8 hv, lv;
        #pragma unroll
        for (int c = 0; c < 8; ++c) {
            float v = buf[c * 9 + s];
            f16 h = (f16)v;
            hv[c] = h;
            lv[c] = (f16)(v - (float)h);
        }
        size_t off = ((size_t)(kgl * 9 + s) * MDIM + o) * 8;
        *(f16x8*)(W3h + off) = hv;
        *(f16x8*)(W3l + off) = lv;
    }
}

// ---------------- 1x1 weight transform (round-11 style: 32B-contiguous per-thread reads) ----
__global__ void w1trans_kernel(const float* __restrict__ w1a,
                               const float* __restrict__ w1b,
                               f16* __restrict__ W1ah, f16* __restrict__ W1al,
                               f16* __restrict__ W1bh, f16* __restrict__ W1bl)
{
    int tid = blockIdx.x * blockDim.x + threadIdx.x;
    const int N1 = G1 * MDIM;
    const float* src; f16 *dh, *dl; int g, o;
    if (tid < N1)            { g = tid / MDIM; o = tid - g * MDIM; src = w1a; dh = W1ah; dl = W1al; }
    else if (tid < 2 * N1)   { int u = tid - N1; g = u / MDIM; o = u - g * MDIM; src = w1b; dh = W1bh; dl = W1bl; }
    else return;

    float v[8];
    #pragma unroll
    for (int j = 0; j < 8; ++j) v[j] = 0.f;
    if (g < 90 && o < 720) {
        #pragma unroll
        for (int j = 0; j < 8; ++j)
            v[j] = src[(size_t)o * 720 + g * 8 + j];
    }
    f16x8 hv, lv;
    #pragma unroll
    for (int j = 0; j < 8; ++j) {
        f16 h = (f16)v[j];
        hv[j] = h;
        lv[j] = (f16)(v[j] - (float)h);
    }
    size_t off = ((size_t)g * MDIM + o) * 8;
    *(f16x8*)(dh + off) = hv;
    *(f16x8*)(dl + off) = lv;
}

// ---------------- upsample+concat -> split-fp16 K8-packed padded-image planes ---------------
__global__ void upsample_kernel(const float* __restrict__ f1,
                                const float* __restrict__ f2,
                                const float* __restrict__ f3,
                                const float* __restrict__ f4,
                                f16* __restrict__ Xhi, f16* __restrict__ Xlo)
{
    int tid = blockIdx.x * blockDim.x + threadIdx.x;
    if (tid >= 90 * GPIX) return;
    int kg = tid / GPIX;
    int gp = tid - kg * GPIX;
    int p  = gp - GUARD;
    float v[8];
    #pragma unroll
    for (int j = 0; j < 8; ++j) v[j] = 0.f;
    if (p >= 0 && p < NPIXP) {
        int b = p / IMG; int rem = p - b * IMG;
        int y = rem / PH; int x = rem - y * PH;
        if (y >= 1 && y <= 96 && x >= 1 && x <= 96) {
            int oy = y - 1, ox = x - 1;
            int c0 = kg * 8;
            if (c0 < 48) {
                #pragma unroll
                for (int j = 0; j < 8; ++j)
                    v[j] = f1[((size_t)(b * 48 + c0 + j)) * HW + oy * 96 + ox];
            } else {
                const float* src; int Cs, Hs, cb;
                if (c0 < 144)      { src = f2; Cs = 96;  Hs = 48; cb = c0 - 48; }
                else if (c0 < 336) { src = f3; Cs = 192; Hs = 24; cb = c0 - 144; }
                else               { src = f4; Cs = 384; Hs = 12; cb = c0 - 336; }
                float scale = (float)(Hs - 1) / 95.0f;
                float yf = oy * scale, xf = ox * scale;
                int y0 = (int)yf, x0 = (int)xf;
                float wy = yf - y0, wx = xf - x0;
                int y1 = min(y0 + 1, Hs - 1), x1 = min(x0 + 1, Hs - 1);
                #pragma unroll
                for (int j = 0; j < 8; ++j) {
                    const float* sb = src + (size_t)(b * Cs + cb + j) * Hs * Hs;
                    float v00 = sb[y0 * Hs + x0], v01 = sb[y0 * Hs + x1];
                    float v10 = sb[y1 * Hs + x0], v11 = sb[y1 * Hs + x1];
                    float r0 = v00 * (1.f - wy) + v10 * wy;
                    float r1 = v01 * (1.f - wy) + v11 * wy;
                    v[j] = r0 * (1.f - wx) + r1 * wx;
                }
            }
        }
    }
    f16x8 hv, lv;
    #pragma unroll
    for (int j = 0; j < 8; ++j) {
        f16 h = (f16)v[j];
        hv[j] = h;
        lv[j] = (f16)(v[j] - (float)h);
    }
    size_t off = (size_t)tid * 8;
    *(f16x8*)(Xhi + off) = hv;
    *(f16x8*)(Xlo + off) = lv;
}

// ---------------- split-fp16 MFMA implicit-GEMM conv: barrier-free + B-reg prefetch ----------
// (round-11 winner, unchanged — the control)
template<int NSTEP, int CONV3>
__global__ __launch_bounds__(256, 3)
void mfma_gemm(const f16* __restrict__ Whi, const f16* __restrict__ Wlo,
               const f16* __restrict__ Bhi_, const f16* __restrict__ Blo_,
               f16* __restrict__ Ohi, f16* __restrict__ Olo,
               const float* __restrict__ alpha, const float* __restrict__ beta,
               int relu)
{
    const int l = blockIdx.x;
    const int xcd = l & 7;
    const int j0 = l >> 3;                // 0..113
    const int ncol = xcd * 19 + j0 / 6;   // 19 n-columns per XCD band
    if (ncol >= 151) return;
    const int m0 = (j0 % 6) * 128;
    const int n0 = ncol * 128;

    const int t = threadIdx.x;
    const int lane = t & 63, wid = t >> 6;
    const int wm = wid >> 1, wn = wid & 1;
    const int quad = lane >> 4, ln = lane & 15;

    f32x4 acc[4][4];
    #pragma unroll
    for (int i = 0; i < 4; ++i)
        #pragma unroll
        for (int j = 0; j < 4; ++j)
            acc[i][j] = (f32x4){0.f, 0.f, 0.f, 0.f};

    const int arow = m0 + wm * 64 + ln;
    const f16* Ah0 = Whi + ((size_t)quad * MDIM + arow) * 8;
    const f16* Al0 = Wlo + ((size_t)quad * MDIM + arow) * 8;
    const size_t astep = (size_t)4 * MDIM * 8;

    const int bcol = n0 + wn * 64 + ln;

    auto brow_of = [&](int step) -> long long {
        const int g = step * 4 + quad;
        if (CONV3) {
            int gc = min(g, 809);
            int kgl = gc / 9;
            int s = gc - kgl * 9;
            int d = (s / 3 - 1) * PH + (s % 3 - 1);
            return (long long)kgl * GPIX + d;
        }
        return (long long)min(g, G1 - 1) * GPIX;
    };

    f16x8 bcur[8], bnxt[8];
    {
        const long long brow = brow_of(0);
        const f16* bh = Bhi_ + (brow + bcol) * 8;
        const f16* bl = Blo_ + (brow + bcol) * 8;
        #pragma unroll
        for (int nt = 0; nt < 4; ++nt) {
            bcur[nt]     = *(const f16x8*)(bh + nt * 128);
            bcur[nt + 4] = *(const f16x8*)(bl + nt * 128);
        }
    }

    for (int step = 0; step < NSTEP; ++step) {
        {
            const long long brow = brow_of(step + 1);
            const f16* bh = Bhi_ + (brow + bcol) * 8;
            const f16* bl = Blo_ + (brow + bcol) * 8;
            #pragma unroll
            for (int nt = 0; nt < 4; ++nt) {
                bnxt[nt]     = *(const f16x8*)(bh + nt * 128);
                bnxt[nt + 4] = *(const f16x8*)(bl + nt * 128);
            }
        }
        const f16* Ah = Ah0 + (size_t)step * astep;
        const f16* Al = Al0 + (size_t)step * astep;
        f16x8 av[8];
        #pragma unroll
        for (int mt = 0; mt < 4; ++mt) {
            av[mt]     = *(const f16x8*)(Ah + mt * 128);
            av[mt + 4] = *(const f16x8*)(Al + mt * 128);
        }
        #pragma unroll
        for (int mt = 0; mt < 4; ++mt)
            #pragma unroll
            for (int nt = 0; nt < 4; ++nt) {
                acc[mt][nt] = __builtin_amdgcn_mfma_f32_16x16x32_f16(av[mt],     bcur[nt],     acc[mt][nt], 0, 0, 0);
                acc[mt][nt] = __builtin_amdgcn_mfma_f32_16x16x32_f16(av[mt],     bcur[nt + 4], acc[mt][nt], 0, 0, 0);
                acc[mt][nt] = __builtin_amdgcn_mfma_f32_16x16x32_f16(av[mt + 4], bcur[nt],     acc[mt][nt], 0, 0, 0);
            }
        #pragma unroll
        for (int i = 0; i < 8; ++i) bcur[i] = bnxt[i];
    }

    #pragma unroll
    for (int mt = 0; mt < 4; ++mt) {
        const int rowb = m0 + wm * 64 + mt * 16 + quad * 4;
        const float4 a4 = *(const float4*)(alpha + rowb);
        const float4 b4 = *(const float4*)(beta + rowb);
        const size_t kg = rowb >> 3;
        const int sub = rowb & 7;
        #pragma unroll
        for (int nt = 0; nt < 4; ++nt) {
            const int P = n0 + wn * 64 + nt * 16 + ln;
            float v0 = acc[mt][nt][0] * a4.x + b4.x;
            float v1 = acc[mt][nt][1] * a4.y + b4.y;
            float v2 = acc[mt][nt][2] * a4.z + b4.z;
            float v3 = acc[mt][nt][3] * a4.w + b4.w;
            if (relu) {
                v0 = fmaxf(v0, 0.f); v1 = fmaxf(v1, 0.f);
                v2 = fmaxf(v2, 0.f); v3 = fmaxf(v3, 0.f);
            }
            f16 h0 = (f16)v0, h1 = (f16)v1, h2 = (f16)v2, h3 = (f16)v3;
            f16x4 hv = {h0, h1, h2, h3};
            f16x4 lv = {(f16)(v0 - (float)h0), (f16)(v1 - (float)h1),
                        (f16)(v2 - (float)h2), (f16)(v3 - (float)h3)};
            size_t o = (kg * GPIX + P) * 8 + sub;
            *(f16x4*)(Ohi + o) = hv;
            *(f16x4*)(Olo + o) = lv;
        }
    }
}

// ---------------- head v2: 16 lanes/pixel, single pass over Y (values held in registers) -----
// (round-14 exact)
__global__ __launch_bounds__(256)
void head_kernel(const f16* __restrict__ Yhi, const f16* __restrict__ Ylo,  // at GUARD
                 const float* __restrict__ lng, const float* __restrict__ lnb,
                 const float* __restrict__ protoN,
                 const float* __restrict__ lmg, const float* __restrict__ lmb,
                 float* __restrict__ out)
{
    const int t = threadIdx.x;
    const int wv = t >> 6, lane = t & 63;
    const int pw = lane >> 4, sub = lane & 15;
    const int p = blockIdx.x * 16 + wv * 4 + pw;     // 0..18431
    const int b = p / HW; const int r = p - b * HW;
    const int y = r / 96; const int x = r - y * 96;
    const size_t P = (size_t)b * IMG + (y + 1) * PH + (x + 1);

    f16x8 xh[6], xl[6];
    float s1 = 0.f, s2 = 0.f;
    #pragma unroll
    for (int k = 0; k < 6; ++k) {
        int kg = sub + 16 * k;
        if (kg < 90) {
            xh[k] = *(const f16x8*)(Yhi + ((size_t)kg * GPIX + P) * 8);
            xl[k] = *(const f16x8*)(Ylo + ((size_t)kg * GPIX + P) * 8);
            #pragma unroll
            for (int j = 0; j < 8; ++j) {
                float v = (float)xh[k][j] + (float)xl[k][j];
                s1 += v; s2 += v * v;
            }
        }
    }
    #pragma unroll
    for (int m = 1; m < 16; m <<= 1) {
        s1 += __shfl_xor(s1, m);
        s2 += __shfl_xor(s2, m);
    }
    float mu  = s1 * (1.0f / 720.0f);
    float var = s2 * (1.0f / 720.0f) - mu * mu;
    float inv = rsqrtf(var + 1e-5f);

    float dots[20];
    #pragma unroll
    for (int q = 0; q < 20; ++q) dots[q] = 0.f;
    float nrm = 0.f;
    #pragma unroll
    for (int k = 0; k < 6; ++k) {
        int kg = sub + 16 * k;
        if (kg < 90) {
            const int c0 = kg * 8;
            #pragma unroll
            for (int j = 0; j < 8; ++j) {
                const int c = c0 + j;
                float v = ((float)xh[k][j] + (float)xl[k][j] - mu) * inv * lng[c] + lnb[c];
                nrm += v * v;
                #pragma unroll
                for (int q = 0; q < 20; ++q)
                    dots[q] = fmaf(v, protoN[q * 720 + c], dots[q]);
            }
        }
    }
    #pragma unroll
    for (int m = 1; m < 16; m <<= 1) {
        nrm += __shfl_xor(nrm, m);
        #pragma unroll
        for (int q = 0; q < 20; ++q) dots[q] += __shfl_xor(dots[q], m);
    }

    if (sub == 0) {
        float rn = 1.0f / fmaxf(sqrtf(nrm), 1e-12f);
        float m0v = -FLT_MAX, m1v = -FLT_MAX;
        #pragma unroll
        for (int q = 0; q < 10; ++q) m0v = fmaxf(m0v, dots[q]);
        #pragma unroll
        for (int q = 10; q < 20; ++q) m1v = fmaxf(m1v, dots[q]);
        m0v *= rn; m1v *= rn;
        float mu2 = 0.5f * (m0v + m1v);
        float dv  = m0v - mu2;
        float va  = dv * dv;
        float iv  = rsqrtf(va + 1e-5f);
        float o0 = (m0v - mu2) * iv * lmg[0] + lmb[0];
        float o1 = (m1v - mu2) * iv * lmg[1] + lmb[1];
        out[b * (2 * HW) + r]      = o0;
        out[b * (2 * HW) + HW + r] = o1;
    }
}

extern "C" void kernel_launch(void* const* d_in, const int* in_sizes, int n_in,
                              void* d_out, int out_size, void* d_ws, size_t ws_size,
                              hipStream_t stream)
{
    const float* feat1      = (const float*)d_in[0];
    const float* feat2      = (const float*)d_in[1];
    const float* feat3      = (const float*)d_in[2];
    const float* feat4      = (const float*)d_in[3];
    const float* cls_w      = (const float*)d_in[4];
    const float* cls_b      = (const float*)d_in[5];
    const float* cls_bn_g   = (const float*)d_in[6];
    const float* cls_bn_b   = (const float*)d_in[7];
    const float* cls_bn_rm  = (const float*)d_in[8];
    const float* cls_bn_rv  = (const float*)d_in[9];
    const float* proj_w1    = (const float*)d_in[10];
    const float* proj_b1    = (const float*)d_in[11];
    const float* proj_bn_g  = (const float*)d_in[12];
    const float* proj_bn_b  = (const float*)d_in[13];
    const float* proj_bn_rm = (const float*)d_in[14];
    const float* proj_bn_rv = (const float*)d_in[15];
    const float* proj_w2    = (const float*)d_in[16];
    const float* proj_b2    = (const float*)d_in[17];
    const float* ln_feat_g  = (const float*)d_in[18];
    const float* ln_feat_b  = (const float*)d_in[19];
    const float* ln_mask_g  = (const float*)d_in[20];
    const float* ln_mask_b  = (const float*)d_in[21];
    const float* protos     = (const float*)d_in[22];

    const size_t PLANEH = (size_t)NKG_ACT * GPIX * 8;    // 15,040,512 halves
    const size_t W3SZ   = (size_t)G3 * MDIM * 8;         // 5,013,504
    const size_t W1SZ   = (size_t)G1 * MDIM * 8;         // 589,824

    f16* Xhi  = (f16*)d_ws;
    f16* Xlo  = Xhi + PLANEH;
    f16* Yhi  = Xlo + PLANEH;
    f16* Ylo  = Yhi + PLANEH;
    f16* W3h  = Ylo + PLANEH;
    f16* W3l  = W3h + W3SZ;
    f16* W1ah = W3l + W3SZ;
    f16* W1al = W1ah + W1SZ;
    f16* W1bh = W1al + W1SZ;
    f16* W1bl = W1bh + W1SZ;
    float* alphas = (float*)(W1bl + W1SZ);
    float* betas  = alphas + 3 * MDIM;
    float* protoN = betas + 3 * MDIM;                    // [20][720]

    prep_kernel<<<21, 256, 0, stream>>>(cls_b, cls_bn_g, cls_bn_b, cls_bn_rm, cls_bn_rv,
                                        proj_b1, proj_bn_g, proj_bn_b, proj_bn_rm, proj_bn_rv,
                                        proj_b2, protos, alphas, betas, protoN);
    {
        int total = 91 * MDIM;                            // (kgl 0..90) x 768
        w3trans_kernel<<<(total + 255) / 256, 256, 0, stream>>>(cls_w, W3h, W3l);
    }
    {
        int total = 2 * G1 * MDIM;
        w1trans_kernel<<<(total + 255) / 256, 256, 0, stream>>>(proj_w1, proj_w2,
                                                                W1ah, W1al, W1bh, W1bl);
    }
    {
        int total = 90 * GPIX;
        upsample_kernel<<<(total + 255) / 256, 256, 0, stream>>>(feat1, feat2, feat3, feat4,
                                                                 Xhi, Xlo);
    }

    const size_t GOFF = (size_t)GUARD * 8;
    const int NBLK = 912;             // 8 XCD bands x 114 (19 ncols x 6 m-tiles); 6 no-op tails
    mfma_gemm<203, 1><<<NBLK, 256, 0, stream>>>(W3h, W3l, Xhi + GOFF, Xlo + GOFF,
                                                Yhi + GOFF, Ylo + GOFF,
                                                alphas, betas, 1);
    mfma_gemm<23, 0><<<NBLK, 256, 0, stream>>>(W1ah, W1al, Yhi + GOFF, Ylo + GOFF,
                                               Xhi + GOFF, Xlo + GOFF,
                                               alphas + MDIM, betas + MDIM, 1);
    mfma_gemm<23, 0><<<NBLK, 256, 0, stream>>>(W1bh, W1bl, Xhi + GOFF, Xlo + GOFF,
                                               Yhi + GOFF, Ylo + GOFF,
                                               alphas + 2 * MDIM, betas + 2 * MDIM, 0);

    head_kernel<<<HW * 2 / 16, 256, 0, stream>>>(Yhi + GOFF, Ylo + GOFF,
                                                 ln_feat_g, ln_feat_b, protoN,
                                                 ln_mask_g, ln_mask_b, (float*)d_out);
}